// Round 6
// baseline (512.056 us; speedup 1.0000x reference)
//
#include <hip/hip_runtime.h>

#define T_STEPS 512
#define BT 16          // batches per block (one 16-row MFMA tile)
#define XSTRIDE 520    // padded x row stride (floats)
#define HSTRIDE 72     // padded h row stride (shorts): 144B rows -> bf16x8 reads 16B-aligned

typedef __attribute__((ext_vector_type(8))) short bf16x8;
typedef __attribute__((ext_vector_type(4))) float f32x4;

#if __has_builtin(__builtin_amdgcn_exp2f)
#define EXP2F(x) __builtin_amdgcn_exp2f(x)
#else
#define EXP2F(x) exp2f(x)
#endif
#define RCPF(x) __builtin_amdgcn_rcpf(x)

__device__ __forceinline__ short f2bf(float f) {
    union { float f; unsigned u; } v; v.f = f;
    unsigned r = v.u + 0x7fffu + ((v.u >> 16) & 1u);   // RNE
    return (short)(r >> 16);
}
__device__ __forceinline__ float bf2f(short s) {
    union { float f; unsigned u; } v;
    v.u = ((unsigned)(unsigned short)s) << 16;
    return v.f;
}

// LOG2E scaling folded into weights/bias:
//   i,f,o rows scaled by -log2e  -> sig(z)  = rcp(1 + exp2(acc))
//   g rows scaled by +2*log2e    -> tanh(z) = 1 - 2*rcp(1 + exp2(acc))
#define NLOG2E  (-1.4426950408889634f)
#define P2LOG2E ( 2.8853900817779268f)

__global__ __launch_bounds__(512) void lstm_persist(
    const float* __restrict__ x,      // [B, T]
    const float* __restrict__ W_ih,   // [256]
    const float* __restrict__ W_hh,   // [256,64]
    const float* __restrict__ b_ih,   // [256]
    const float* __restrict__ b_hh,   // [256]
    const float* __restrict__ W_fc,   // [64]
    const float* __restrict__ b_fc,   // [1]
    float* __restrict__ out)          // [B]
{
    __shared__ __align__(16) float  x_lds[BT * XSTRIDE];        // 33.3 KB
    __shared__ __align__(16) short  hbuf[2][2][BT][HSTRIDE];    // 9.2 KB [buf][hi/lo][b][k]

    const int tid  = threadIdx.x;
    const int wave = tid >> 6;     // 0..7
    const int lane = tid & 63;
    const int l15  = lane & 15;
    const int quad = lane >> 4;    // 0..3
    const int s    = wave & 3;     // column slice: k in [16s, 16s+16)
    const int p    = wave >> 2;    // row-half: owns acc regs {2p, 2p+1} (rows quad*4+2p+j)
    const int b0   = blockIdx.x * BT;

    // ---- stage x[b0..b0+15][0..511] into LDS (coalesced float4) ----
    {
        const float* xg = x + (size_t)b0 * T_STEPS;
        #pragma unroll
        for (int i = 0; i < 4; ++i) {
            int f4 = tid + i * 512;        // 0..2047
            int b  = f4 >> 7;              // 128 float4 per row
            int t4 = f4 & 127;
            float4 v = reinterpret_cast<const float4*>(xg + (size_t)b * T_STEPS)[t4];
            reinterpret_cast<float4*>(&x_lds[b * XSTRIDE + t4 * 4])[0] = v;
        }
    }
    // ---- zero h buffer 0 (hi + lo) ----
    for (int i = tid; i < 2 * BT * HSTRIDE; i += 512) (&hbuf[0][0][0][0])[i] = 0;

    // ---- resident W_hh fragments for ALL 4 gates (exp2-scaled, hi/lo split) ----
    // B-frag: lane holds B[k = quad*8+j (+32*kh)][n = l15]
    bf16x8 Bhi[4][2], Blo[4][2];
    float bias_s[4], wih_s[4];
    const int kcol = s * 16 + l15;
    #pragma unroll
    for (int tgt = 0; tgt < 4; ++tgt) {            // 0=i 1=f 2=g 3=o
        float sc = (tgt == 2) ? P2LOG2E : NLOG2E;
        int n = tgt * 64 + kcol;                   // gate row
        bias_s[tgt] = sc * (b_ih[n] + b_hh[n]);
        wih_s[tgt]  = sc * W_ih[n];
        #pragma unroll
        for (int kh = 0; kh < 2; ++kh) {
            const float* wr = W_hh + n * 64 + kh * 32 + quad * 8;
            bf16x8 hi, lo;
            #pragma unroll
            for (int jj = 0; jj < 8; ++jj) {
                float w = sc * wr[jj];
                short h16 = f2bf(w);
                hi[jj] = h16;
                lo[jj] = f2bf(w - bf2f(h16));
            }
            Bhi[tgt][kh] = hi;
            Blo[tgt][kh] = lo;
        }
    }

    float cc[2] = {0.f, 0.f};                 // c for owned rows quad*4 + 2p + {0,1}
    const int aoff = l15 * HSTRIDE + quad * 8;

    __syncthreads();

    for (int t = 0; t < T_STEPS; ++t) {
        const int rb = t & 1, wb = rb ^ 1;

        // A fragments (hi/lo bf16 h), kh = 0 / +32; 16B-aligned
        const short* hhi = &hbuf[rb][0][0][0];
        const short* hlo = &hbuf[rb][1][0][0];
        bf16x8 ahi0 = *reinterpret_cast<const bf16x8*>(hhi + aoff);
        bf16x8 ahi1 = *reinterpret_cast<const bf16x8*>(hhi + aoff + 32);
        bf16x8 alo0 = *reinterpret_cast<const bf16x8*>(hlo + aoff);
        bf16x8 alo1 = *reinterpret_cast<const bf16x8*>(hlo + aoff + 32);

        // x values for owned rows only
        float xv[2];
        #pragma unroll
        for (int j = 0; j < 2; ++j)
            xv[j] = x_lds[(quad * 4 + 2 * p + j) * XSTRIDE + t];

        // init only owned acc entries (others 0 -> their results are discarded)
        f32x4 acc[4];
        #pragma unroll
        for (int tgt = 0; tgt < 4; ++tgt) {
            acc[tgt] = (f32x4){0.f, 0.f, 0.f, 0.f};
            #pragma unroll
            for (int j = 0; j < 2; ++j)
                acc[tgt][2 * p + j] = bias_s[tgt] + wih_s[tgt] * xv[j];
        }
        // 3-pass split-bf16: Ahi*Bhi + Alo*Bhi + Ahi*Blo  (~fp32 precision)
        #pragma unroll
        for (int tgt = 0; tgt < 4; ++tgt) {
            acc[tgt] = __builtin_amdgcn_mfma_f32_16x16x32_bf16(ahi0, Bhi[tgt][0], acc[tgt], 0, 0, 0);
            acc[tgt] = __builtin_amdgcn_mfma_f32_16x16x32_bf16(ahi1, Bhi[tgt][1], acc[tgt], 0, 0, 0);
            acc[tgt] = __builtin_amdgcn_mfma_f32_16x16x32_bf16(alo0, Bhi[tgt][0], acc[tgt], 0, 0, 0);
            acc[tgt] = __builtin_amdgcn_mfma_f32_16x16x32_bf16(alo1, Bhi[tgt][1], acc[tgt], 0, 0, 0);
            acc[tgt] = __builtin_amdgcn_mfma_f32_16x16x32_bf16(ahi0, Blo[tgt][0], acc[tgt], 0, 0, 0);
            acc[tgt] = __builtin_amdgcn_mfma_f32_16x16x32_bf16(ahi1, Blo[tgt][1], acc[tgt], 0, 0, 0);
        }

        // epilogue for owned rows only (in-lane: this lane has i,f,g,o of its (b,k))
        #pragma unroll
        for (int j = 0; j < 2; ++j) {
            int r = 2 * p + j;
            float iv = RCPF(1.0f + EXP2F(acc[0][r]));
            float fv = RCPF(1.0f + EXP2F(acc[1][r]));
            float gv = 1.0f - 2.0f * RCPF(1.0f + EXP2F(acc[2][r]));
            float ov = RCPF(1.0f + EXP2F(acc[3][r]));
            float c = fv * cc[j] + iv * gv;
            cc[j] = c;
            float th = 1.0f - 2.0f * RCPF(1.0f + EXP2F(c * P2LOG2E));  // tanh(c)
            float hv = ov * th;
            short hh = f2bf(hv);
            short hl = f2bf(hv - bf2f(hh));
            int b = quad * 4 + r;
            hbuf[wb][0][b][kcol] = hh;
            hbuf[wb][1][b][kcol] = hl;
        }
        __syncthreads();
    }

    // ---- final FC: h final lives in hbuf[0] (t=511 wrote wb=0) ----
    if (tid < 16) {
        int b = tid;
        float ssum = b_fc[0];
        #pragma unroll 4
        for (int k = 0; k < 64; ++k)
            ssum += (bf2f(hbuf[0][0][b][k]) + bf2f(hbuf[0][1][b][k])) * W_fc[k];
        out[b0 + b] = ssum;
    }
}

extern "C" void kernel_launch(void* const* d_in, const int* in_sizes, int n_in,
                              void* d_out, int out_size, void* d_ws, size_t ws_size,
                              hipStream_t stream) {
    const float* x    = (const float*)d_in[0];
    const float* W_ih = (const float*)d_in[1];
    const float* W_hh = (const float*)d_in[2];
    const float* b_ih = (const float*)d_in[3];
    const float* b_hh = (const float*)d_in[4];
    const float* W_fc = (const float*)d_in[5];
    const float* b_fc = (const float*)d_in[6];
    float* out = (float*)d_out;
    const int B = in_sizes[0] / T_STEPS;   // 4096
    lstm_persist<<<dim3(B / BT), dim3(512), 0, stream>>>(
        x, W_ih, W_hh, b_ih, b_hh, W_fc, b_fc, out);
}